// Round 4
// baseline (683.551 us; speedup 1.0000x reference)
//
#include <hip/hip_runtime.h>

// RelPosEmbedder: out[p,c] = tok[p,:42] @ W[66:108,c] + W[d_res,c] + ent*W[108,c] + W[109+d_chain,c]
// Barrier-free design:
//  - A fragment loaded DIRECTLY global->reg (lane = one tok row, 8 consecutive floats per frag quad)
//  - ent/chain one-hots computed in-register and folded into A cols 42..48 (B rows 66..114)
//  - d_res epilogue row fetched from per-lane flags via __shfl, W[d_res] from f32 LDS table
//  - 1-deep register prefetch of next chunk; only one __syncthreads per block (W table staging)

typedef __attribute__((ext_vector_type(8))) short short8;
typedef __attribute__((ext_vector_type(4))) float floatx4;

#define NSEQ    1024
#define CZ      128
#define CHUNK   64          // pairs per chunk (16 per wave x 4 waves)
#define NCHUNK  8           // chunks per block -> 512 pairs/block
#define THREADS 256
#define KW      49          // folded K width: 42 tok + 1 ent + 6 chain
#define WROW    132         // f32 lds_W row stride (128 + 4 pad)
#define NWROWS  66          // gather rows 0..65 (d_res)

__device__ __forceinline__ unsigned int packbf2(float x, float y) {
    // D.lo = bf16(x), D.hi = bf16(y), RNE (gfx950 v_cvt_pk_bf16_f32)
    unsigned int r;
    asm("v_cvt_pk_bf16_f32 %0, %1, %2" : "=v"(r) : "v"(x), "v"(y));
    return r;
}

struct Pref {
    float2 t0, t1, t2, t3;   // a0: tok cols q*8 .. q*8+7
    float2 t4, t5, t6, t7;   // a1 (q==0): tok cols 32..39
    float2 t8;               // a1 (q==1): tok cols 40,41
    int aj, sj, ej, rj;      // metadata for pair n
};

__global__ __launch_bounds__(THREADS, 3) void relpos_kernel(
    const float* __restrict__ tok,   // [N*N, 42] f32
    const float* __restrict__ W,     // [115, 128] f32
    const int* __restrict__ asym,
    const int* __restrict__ sym,
    const int* __restrict__ eid,
    const int* __restrict__ res,
    float* __restrict__ out)         // [N*N, 128] f32
{
    __shared__ __align__(16) float lds_W[NWROWS * WROW];

    const int tid  = threadIdx.x;
    const int lane = tid & 63;
    const int wv   = tid >> 6;
    const int n    = lane & 15;   // A row m / C col within 16-tile / pair owner index
    const int q    = lane >> 4;   // quad

    // ---- one-time: stage d_res gather rows 0..65 (f32, padded stride) ----
    for (int u4 = tid; u4 < NWROWS * 32; u4 += THREADS) {
        int row = u4 >> 5, c4 = (u4 & 31) << 2;
        *(float4*)&lds_W[row * WROW + c4] = *(const float4*)&W[row * CZ + c4];
    }

    // ---- one-time: B fragments (W rows 66..114 as bf16, K zero-padded to 64) ----
    short8 bfrag[2][8];
    #pragma unroll
    for (int ks = 0; ks < 2; ++ks) {
        #pragma unroll
        for (int nt = 0; nt < 8; ++nt) {
            unsigned int bu[4];
            #pragma unroll
            for (int j2 = 0; j2 < 4; ++j2) {
                int k0 = ks * 32 + q * 8 + j2 * 2, k1 = k0 + 1;
                float x = (k0 < KW) ? W[(66 + k0) * CZ + nt * 16 + n] : 0.f;
                float y = (k1 < KW) ? W[(66 + k1) * CZ + nt * 16 + n] : 0.f;
                bu[j2] = packbf2(x, y);
            }
            __builtin_memcpy(&bfrag[ks][nt], bu, 16);
        }
    }

    const int pblock = blockIdx.x * (CHUNK * NCHUNK);
    const int irow = pblock >> 10;                       // i constant per block (512 pairs within a row-half)
    const int ai = asym[irow], si = sym[irow], ei = eid[irow], ri = res[irow];
    const int jb = (pblock & (NSEQ - 1)) + wv * 16 + n;  // j for this lane's pair, chunk 0

    __syncthreads();   // lds_W visible

    Pref cur, nxt;
    {   // ---- load chunk 0 ----
        const float2* base = (const float2*)(tok + (size_t)(pblock + wv * 16 + n) * 42);
        cur.t0 = base[q * 4 + 0]; cur.t1 = base[q * 4 + 1];
        cur.t2 = base[q * 4 + 2]; cur.t3 = base[q * 4 + 3];
        float2 z = {0.f, 0.f};
        cur.t4 = z; cur.t5 = z; cur.t6 = z; cur.t7 = z; cur.t8 = z;
        if (q == 0) { cur.t4 = base[16]; cur.t5 = base[17]; cur.t6 = base[18]; cur.t7 = base[19]; }
        if (q == 1) { cur.t8 = base[20]; }
        cur.aj = asym[jb]; cur.sj = sym[jb]; cur.ej = eid[jb]; cur.rj = res[jb];
    }

    for (int ch = 0; ch < NCHUNK; ++ch) {
        const int p0 = pblock + ch * CHUNK;

        // ---- flags for pair n (this lane owns pair wv*16+n) ----
        bool cs = (ai == cur.aj), es = (ei == cur.ej);
        int ro = ri - cur.rj + 32; ro = ro < 0 ? 0 : (ro > 64 ? 64 : ro);
        int dres = cs ? ro : 65;
        int co = si - cur.sj + 2; co = co < 0 ? 0 : (co > 4 ? 4 : co);
        int dch = (cs || !es) ? 5 : co;
        const unsigned int one = 0x3F80u;   // bf16(1.0)

        // ---- build A fragments in-register ----
        unsigned int au[4], a1u[4];
        au[0] = packbf2(cur.t0.x, cur.t0.y);
        au[1] = packbf2(cur.t1.x, cur.t1.y);
        au[2] = packbf2(cur.t2.x, cur.t2.y);
        au[3] = packbf2(cur.t3.x, cur.t3.y);
        if (q == 0) {                       // k 32..39: tok cols 32..39
            a1u[0] = packbf2(cur.t4.x, cur.t4.y);
            a1u[1] = packbf2(cur.t5.x, cur.t5.y);
            a1u[2] = packbf2(cur.t6.x, cur.t6.y);
            a1u[3] = packbf2(cur.t7.x, cur.t7.y);
        } else if (q == 1) {                // k 40..47: tok 40,41 | ent | chain oh 0..4
            a1u[0] = packbf2(cur.t8.x, cur.t8.y);
            a1u[1] = (es ? one : 0u)        | ((dch == 0 ? one : 0u) << 16);
            a1u[2] = (dch == 1 ? one : 0u)  | ((dch == 2 ? one : 0u) << 16);
            a1u[3] = (dch == 3 ? one : 0u)  | ((dch == 4 ? one : 0u) << 16);
        } else if (q == 2) {                // k 48..55: chain oh 5, rest pad
            a1u[0] = (dch == 5 ? one : 0u);
            a1u[1] = 0u; a1u[2] = 0u; a1u[3] = 0u;
        } else {                            // k 56..63: pad
            a1u[0] = 0u; a1u[1] = 0u; a1u[2] = 0u; a1u[3] = 0u;
        }
        short8 a0, a1;
        __builtin_memcpy(&a0, au, 16);
        __builtin_memcpy(&a1, a1u, 16);

        // ---- prefetch next chunk (latency hides under MFMA + epilogue) ----
        if (ch + 1 < NCHUNK) {
            const float2* base = (const float2*)(tok + (size_t)(p0 + CHUNK + wv * 16 + n) * 42);
            nxt.t0 = base[q * 4 + 0]; nxt.t1 = base[q * 4 + 1];
            nxt.t2 = base[q * 4 + 2]; nxt.t3 = base[q * 4 + 3];
            float2 z = {0.f, 0.f};
            nxt.t4 = z; nxt.t5 = z; nxt.t6 = z; nxt.t7 = z; nxt.t8 = z;
            if (q == 0) { nxt.t4 = base[16]; nxt.t5 = base[17]; nxt.t6 = base[18]; nxt.t7 = base[19]; }
            if (q == 1) { nxt.t8 = base[20]; }
            int j = jb + (ch + 1) * CHUNK;
            nxt.aj = asym[j]; nxt.sj = sym[j]; nxt.ej = eid[j]; nxt.rj = res[j];
        }

        // ---- MFMA: 16 pairs x 128 channels per wave ----
        floatx4 acc[8];
        #pragma unroll
        for (int nt = 0; nt < 8; ++nt) {
            floatx4 z4 = {0.f, 0.f, 0.f, 0.f};
            z4 = __builtin_amdgcn_mfma_f32_16x16x32_bf16(a0, bfrag[0][nt], z4, 0, 0, 0);
            z4 = __builtin_amdgcn_mfma_f32_16x16x32_bf16(a1, bfrag[1][nt], z4, 0, 0, 0);
            acc[nt] = z4;
        }

        // ---- epilogue: W[d_res] add (f32 LDS), store ----
        // C/D layout: col = lane&15 (per nt tile), row = q*4 + r; d_res for row m owned by lane m
        #pragma unroll
        for (int r = 0; r < 4; ++r) {
            int dres_r = __shfl(dres, q * 4 + r, 64);
            const float* wres = lds_W + dres_r * WROW + n;
            float* op = out + (size_t)(p0 + wv * 16 + q * 4 + r) * CZ + n;
            #pragma unroll
            for (int nt = 0; nt < 8; ++nt)
                op[nt * 16] = acc[nt][r] + wres[nt * 16];
        }

        if (ch + 1 < NCHUNK) cur = nxt;
    }
}

extern "C" void kernel_launch(void* const* d_in, const int* in_sizes, int n_in,
                              void* d_out, int out_size, void* d_ws, size_t ws_size,
                              hipStream_t stream) {
    const float* tok = (const float*)d_in[0];   // rel_tok_feat f32
    const float* W   = (const float*)d_in[1];   // W f32
    const int* asym  = (const int*)d_in[2];
    const int* sym   = (const int*)d_in[3];
    const int* eid   = (const int*)d_in[4];
    const int* res   = (const int*)d_in[5];
    float* out = (float*)d_out;

    const int npairs = NSEQ * NSEQ;
    const int grid = npairs / (CHUNK * NCHUNK);  // 2048 blocks
    hipLaunchKernelGGL(relpos_kernel, dim3(grid), dim3(THREADS), 0, stream,
                       tok, W, asym, sym, eid, res, out);
}